// Round 12
// baseline (4890.545 us; speedup 1.0000x reference)
//
#include <hip/hip_runtime.h>

#define BB 1024
#define NN 81
#define EE 1620
#define HH 128
#define G3 384
#define NSTEPS 8

#define HSTR 132     // hRM/smRM/hid row stride (floats)
#define ABSTR 260    // hAB row stride (floats)

typedef __attribute__((ext_vector_type(4))) float f32x4;

// ---- LDS float offsets ----
#define F_H     0            // hRM 81 x 132 = 10692
#define F_R2    10692        // 21060: union{ xs+win | hAB 81x260 | smRM 81x132 | hid 81x132 }
#define F_GOFF  31752        // 82 ints
#define F_GSEND 31834        // 1620 ushorts (810 float slots)
#define F_BM1   32644        // 128
#define F_BASE  32772        // 512
#define F_EXT   33284        // 512
#define F_BST   33796        // B staging: 2 buffers x 2048 floats (2 k4-slices)
#define F_TOT   37892
#define LDS_BYTES (F_TOT * 4)   // 151568 bytes

// ---------------------------------------------------------------------------
// prep_graph: CSR by receiver (int32 edge input) — verified R2/R4-R11.
// ---------------------------------------------------------------------------
__global__ __launch_bounds__(128) void prep_graph(const int* __restrict__ ei,
                                                  int* __restrict__ goff,
                                                  int* __restrict__ gsend) {
    __shared__ int eis[2 * EE];
    __shared__ int cs[NN];
    __shared__ int offs[NN + 1];
    int tid = threadIdx.x;
    for (int i = tid; i < 2 * EE; i += 128) eis[i] = ei[i];
    __syncthreads();
    if (tid < NN) {
        int c = 0;
        for (int e = 0; e < EE; e++) if (eis[EE + e] == tid) c++;
        cs[tid] = c;
    }
    __syncthreads();
    if (tid == 0) {
        int o = 0;
        for (int r = 0; r < NN; r++) { offs[r] = o; o += cs[r]; }
        offs[NN] = o;
    }
    __syncthreads();
    if (tid < NN) {
        int pos = offs[tid];
        for (int e = 0; e < EE; e++) {
            if (eis[EE + e] == tid) gsend[pos++] = eis[e];
        }
        goff[tid] = offs[tid];
    }
    if (tid == 0) goff[NN] = offs[NN];
}

// ---------------------------------------------------------------------------
// prep_wc: Wc[c][o] = sum_m W_ih[c][m] * W_m2[m][o]   (384 x 128)
// ---------------------------------------------------------------------------
__global__ __launch_bounds__(256) void prep_wc(const float* __restrict__ W_ih,
                                               const float* __restrict__ W_m2,
                                               float* __restrict__ Wc) {
    int idx = blockIdx.x * 256 + threadIdx.x;
    if (idx >= G3 * HH) return;
    int c = idx >> 7, o = idx & 127;
    float acc = 0.f;
    for (int m = 0; m < HH; m++) acc += W_ih[c * HH + m] * W_m2[m * HH + o];
    Wc[idx] = acc;
}

// ---------------------------------------------------------------------------
// prep_bias: base[512], ext[512]
// ---------------------------------------------------------------------------
__global__ __launch_bounds__(256) void prep_bias(const float* __restrict__ W_ih,
                                                 const float* __restrict__ b_m2,
                                                 const float* __restrict__ b_ih,
                                                 const float* __restrict__ b_hh,
                                                 float* __restrict__ basev,
                                                 float* __restrict__ extv) {
    int c = blockIdx.x * 256 + threadIdx.x;
    if (c >= 512) return;
    float base, ext;
    if (c < 384) {
        float bwc = 0.f;
        for (int m = 0; m < HH; m++) bwc += W_ih[c * HH + m] * b_m2[m];
        ext = bwc;
        base = (c < 256) ? (b_ih[c] + b_hh[c]) : b_ih[c];
    } else {
        ext = 0.f;
        base = b_hh[c - 128];
    }
    basev[c] = base;
    extv[c] = ext;
}

// ---------------------------------------------------------------------------
// prep_w1q: quad-packed W1: W1q[((k>>2)*256 + c)*4 + (k&3)] = W1[c][k]
// ---------------------------------------------------------------------------
__global__ __launch_bounds__(256) void prep_w1q(const float* __restrict__ W_m1,
                                                float* __restrict__ W1q) {
    int idx = blockIdx.x * 256 + threadIdx.x;   // 128*256
    if (idx >= 128 * 256) return;
    int k = idx >> 8, c = idx & 255;
    float v = (c < 128) ? W_m1[c * 256 + k] : W_m1[(c - 128) * 256 + 128 + k];
    W1q[((k >> 2) * 256 + c) * 4 + (k & 3)] = v;
}

// ---------------------------------------------------------------------------
// prep_wgq: quad-packed gates: Wgq[((k>>2)*384 + c)*4 + (k&3)]
//   = k<128 ? Wc[c][k] : W_hh[c][k-128]      (k in [0,256))
// ---------------------------------------------------------------------------
__global__ __launch_bounds__(256) void prep_wgq(const float* __restrict__ Wc,
                                                const float* __restrict__ W_hh,
                                                float* __restrict__ Wgq) {
    int idx = blockIdx.x * 256 + threadIdx.x;   // 256*384
    if (idx >= 256 * G3) return;
    int k = idx / G3;
    int c = idx - k * G3;
    float v = (k < 128) ? Wc[c * HH + k] : W_hh[c * HH + (k - 128)];
    Wgq[((k >> 2) * G3 + c) * 4 + (k & 3)] = v;
}

// ---------------------------------------------------------------------------
// prep_wo1q: Wo1q[((k>>2)*128 + c)*4 + (k&3)] = W_o1[c][k]
// ---------------------------------------------------------------------------
__global__ __launch_bounds__(256) void prep_wo1q(const float* __restrict__ W_o1,
                                                 float* __restrict__ Wo1q) {
    int idx = blockIdx.x * 256 + threadIdx.x;
    if (idx >= 128 * 128) return;
    int k = idx >> 7, c = idx & 127;
    Wo1q[((k >> 2) * 128 + c) * 4 + (k & 3)] = W_o1[c * HH + k];
}

// ---------------------------------------------------------------------------
// fused_rrn: one workgroup per puzzle, 512 threads (8 waves), fp32.
// R11 post-mortem: per-thread global B loads (12 dwordx4/kc, L2 latency, only
// 2 waves/SIMD) stall VALU at 61%. R12: double-buffered LDS B-staging —
// chunks of 2 k4 (8 k) cooperatively loaded (1 coalesced f32x4/thread),
// compute reads B via ds_read_b128. FMA order unchanged => bit-identical.
// ---------------------------------------------------------------------------
__global__ __launch_bounds__(512, 2) void fused_rrn(
    const float* __restrict__ x,
    const float* __restrict__ W_in, const float* __restrict__ b_in,
    const float* __restrict__ b_m1,
    const float* __restrict__ W1q, const float* __restrict__ Wgq,
    const float* __restrict__ basev, const float* __restrict__ extv,
    const float* __restrict__ Wo1q, const float* __restrict__ b_o1,
    const float* __restrict__ W_o2, const float* __restrict__ b_o2,
    const int* __restrict__ goff_g, const int* __restrict__ gsend_g,
    float* __restrict__ out)
{
    extern __shared__ float smf[];
    float* hRM  = smf + F_H;
    float* reg2 = smf + F_R2;
    int*   goffL = (int*)(smf + F_GOFF);
    unsigned short* gsendL = (unsigned short*)(smf + F_GSEND);
    float* bm1L  = smf + F_BM1;
    float* baseL = smf + F_BASE;
    float* extL  = smf + F_EXT;
    float* Bst   = smf + F_BST;

    const int t   = threadIdx.x;
    const int b   = blockIdx.x;
    const int c32 = t & 31;           // base gate column (cols c32+32j, j<4)
    const int g   = t >> 5;           // row group 0..15
    const int rowBase = g * 5;
    const int nR = (g == 15) ? 6 : 5;
    const int rW = t & 31;            // edge-phase row lane
    const int f8 = 8 * (t >> 5);      // edge-phase feature octet (0..120)
    const int sq = t >> 8, scol = t & 255;   // staging map for C=256 slices
    const int q2 = t >> 7, col2 = t & 127;   // staging map for C=128 slices

    // ---- stage misc + x/W_in (into reg2; used once) ----
    float* xsL  = reg2;          // 810
    float* winL = reg2 + 810;    // 1280
    for (int i = t; i < NN + 1; i += 512) goffL[i] = goff_g[i];
    for (int i = t; i < EE; i += 512) gsendL[i] = (unsigned short)gsend_g[i];
    baseL[t] = basev[t];
    extL[t]  = extv[t];
    if (t < 128) bm1L[t] = b_m1[t];
    for (int i = t; i < NN * 10; i += 512) xsL[i] = x[(long)b * (NN * 10) + i];
    for (int i = t; i < HH * 10; i += 512) winL[i] = W_in[i];
    __syncthreads();

    // ---- input projection: hRM[r][m] ----
    for (int idx = t; idx < NN * HH; idx += 512) {
        int r = idx >> 7, m = idx & 127;
        float acc = b_in[m];
#pragma unroll
        for (int k = 0; k < 10; k++) acc += xsL[r * 10 + k] * winL[m * 10 + k];
        hRM[r * HSTR + m] = acc;
    }
    __syncthreads();

    // ======================= 8 message-passing steps =======================
    for (int step = 0; step < NSTEPS; step++) {
        // ---------- GEMM1: hAB = h @ W1^T (cols c32+32j, 128+c32+32j) ----------
        {
            float accA[6][4], accB[6][4];
#pragma unroll
            for (int i = 0; i < 6; i++)
#pragma unroll
                for (int j = 0; j < 4; j++) { accA[i][j] = 0.f; accB[i][j] = 0.f; }

            f32x4 pf;
            {   // prologue: chunk0 -> buf0; chunk1 -> pf
                f32x4 v0 = *(const f32x4*)(W1q + (sq * 256 + scol) * 4);
                *(f32x4*)(Bst + t * 4) = v0;
                pf = *(const f32x4*)(W1q + ((2 + sq) * 256 + scol) * 4);
            }
            __syncthreads();
            for (int ch = 0; ch < 16; ch++) {
                const int cur = ch & 1;
                if (ch + 1 < 16) *(f32x4*)(Bst + (cur ^ 1) * 2048 + t * 4) = pf;
                if (ch + 2 < 16) pf = *(const f32x4*)(W1q + ((2 * (ch + 2) + sq) * 256 + scol) * 4);
                __syncthreads();
                const float* Bb = Bst + cur * 2048;
#pragma unroll
                for (int kl = 0; kl < 2; kl++) {
                    const int kc = ch * 8 + kl * 4;
                    f32x4 bA[4], bB[4];
#pragma unroll
                    for (int j = 0; j < 4; j++) {
                        bA[j] = *(const f32x4*)(Bb + (kl * 256 + c32 + 32 * j) * 4);
                        bB[j] = *(const f32x4*)(Bb + (kl * 256 + 128 + c32 + 32 * j) * 4);
                    }
#pragma unroll
                    for (int i = 0; i < 6; i++) {
                        if (i < nR) {
                            f32x4 a = *(const f32x4*)(hRM + (rowBase + i) * HSTR + kc);
#pragma unroll
                            for (int j = 0; j < 4; j++)
#pragma unroll
                                for (int kk = 0; kk < 4; kk++) {
                                    accA[i][j] = fmaf(a[kk], bA[j][kk], accA[i][j]);
                                    accB[i][j] = fmaf(a[kk], bB[j][kk], accB[i][j]);
                                }
                        }
                    }
                }
                __syncthreads();
            }
            float* hAB = reg2;
#pragma unroll
            for (int i = 0; i < 6; i++) {
                if (i < nR) {
                    int row = rowBase + i;
#pragma unroll
                    for (int j = 0; j < 4; j++) {
                        hAB[row * ABSTR + c32 + 32 * j] = accA[i][j];
                        hAB[row * ABSTR + 128 + c32 + 32 * j] = accB[i][j];
                    }
                }
            }
        }
        __syncthreads();   // B1: hAB ready

        // ---------- edge aggregation: 3 rows x 8 features per thread ----------
        float sv[3][8];
        {
            float bq[8];
#pragma unroll
            for (int j = 0; j < 8; j++) bq[j] = bm1L[f8 + j];
#pragma unroll
            for (int s = 0; s < 3; s++) {
                int row = rW + 32 * s;
                if (row >= NN) {
#pragma unroll
                    for (int j = 0; j < 8; j++) sv[s][j] = 0.f;
                    continue;
                }
                int e0 = goffL[row], e1 = goffL[row + 1];
                f32x4 hb0 = *(const f32x4*)(reg2 + row * ABSTR + 128 + f8);
                f32x4 hb1 = *(const f32x4*)(reg2 + row * ABSTR + 128 + f8 + 4);
                float hbb[8], ac[8];
#pragma unroll
                for (int j = 0; j < 4; j++) {
                    hbb[j] = hb0[j] + bq[j];
                    hbb[4 + j] = hb1[j] + bq[4 + j];
                    ac[j] = 0.f; ac[4 + j] = 0.f;
                }
                for (int e = e0; e < e1; e++) {
                    int sn = gsendL[e];
                    f32x4 av0 = *(const f32x4*)(reg2 + sn * ABSTR + f8);
                    f32x4 av1 = *(const f32x4*)(reg2 + sn * ABSTR + f8 + 4);
#pragma unroll
                    for (int j = 0; j < 4; j++) {
                        ac[j]     += fmaxf(av0[j] + hbb[j], 0.f);
                        ac[4 + j] += fmaxf(av1[j] + hbb[4 + j], 0.f);
                    }
                }
#pragma unroll
                for (int j = 0; j < 8; j++) sv[s][j] = ac[j];
            }
        }
        __syncthreads();   // B2: hAB reads done, reg2 reusable as smRM
        {
#pragma unroll
            for (int s = 0; s < 3; s++) {
                int row = rW + 32 * s;
                if (row >= NN) continue;
                f32x4 v0 = {sv[s][0], sv[s][1], sv[s][2], sv[s][3]};
                f32x4 v1 = {sv[s][4], sv[s][5], sv[s][6], sv[s][7]};
                *(f32x4*)(reg2 + row * HSTR + f8) = v0;
                *(f32x4*)(reg2 + row * HSTR + f8 + 4) = v1;
            }
        }
        __syncthreads();   // B3: smRM ready

        // ---------- GEMM2 split passes (B staged in LDS) ----------
        {
            const float* smRM = reg2;
            float rg_[6][4], z[6][4];
            // ---- pass1: rr, zz over sm (k4 0..31) then h (k4 32..63)
            {
                float rr[6][4], zz[6][4];
#pragma unroll
                for (int i = 0; i < 6; i++)
#pragma unroll
                    for (int j = 0; j < 4; j++) { rr[i][j] = 0.f; zz[i][j] = 0.f; }

                f32x4 pf;
                {
                    f32x4 v0 = *(const f32x4*)(Wgq + (sq * G3 + scol) * 4);
                    *(f32x4*)(Bst + t * 4) = v0;
                    pf = *(const f32x4*)(Wgq + ((2 + sq) * G3 + scol) * 4);
                }
                __syncthreads();
                for (int ch = 0; ch < 32; ch++) {
                    const int cur = ch & 1;
                    if (ch + 1 < 32) *(f32x4*)(Bst + (cur ^ 1) * 2048 + t * 4) = pf;
                    if (ch + 2 < 32) pf = *(const f32x4*)(Wgq + ((2 * (ch + 2) + sq) * G3 + scol) * 4);
                    __syncthreads();
                    const float* Bb = Bst + cur * 2048;
                    const float* Ab = (ch < 16) ? smRM : hRM;
                    const int kcb = (ch & 15) * 8;
#pragma unroll
                    for (int kl = 0; kl < 2; kl++) {
                        const int kc = kcb + kl * 4;
                        f32x4 bR[4], bZ[4];
#pragma unroll
                        for (int j = 0; j < 4; j++) {
                            bR[j] = *(const f32x4*)(Bb + (kl * 256 + c32 + 32 * j) * 4);
                            bZ[j] = *(const f32x4*)(Bb + (kl * 256 + 128 + c32 + 32 * j) * 4);
                        }
#pragma unroll
                        for (int i = 0; i < 6; i++) {
                            if (i < nR) {
                                f32x4 a = *(const f32x4*)(Ab + (rowBase + i) * HSTR + kc);
#pragma unroll
                                for (int j = 0; j < 4; j++)
#pragma unroll
                                    for (int kk = 0; kk < 4; kk++) {
                                        rr[i][j] = fmaf(a[kk], bR[j][kk], rr[i][j]);
                                        zz[i][j] = fmaf(a[kk], bZ[j][kk], zz[i][j]);
                                    }
                            }
                        }
                    }
                    __syncthreads();
                }
#pragma unroll
                for (int i = 0; i < 6; i++) {
                    if (i < nR) {
                        int row = rowBase + i;
                        float cf = (float)(goffL[row + 1] - goffL[row]);
#pragma unroll
                        for (int j = 0; j < 4; j++) {
                            int cc = c32 + 32 * j;
                            float g0 = rr[i][j] + baseL[cc] + cf * extL[cc];
                            float g1 = zz[i][j] + baseL[128 + cc] + cf * extL[128 + cc];
                            rg_[i][j] = 1.f / (1.f + __expf(-g0));
                            z[i][j]   = 1.f / (1.f + __expf(-g1));
                        }
                    }
                }
            }
            // ---- pass2a: nh over h (k4 32..63, N cols) -> tmp = rg_*(nh+base3)
            float tmp[6][4];
            {
                float nh[6][4];
#pragma unroll
                for (int i = 0; i < 6; i++)
#pragma unroll
                    for (int j = 0; j < 4; j++) nh[i][j] = 0.f;

                f32x4 pf;
                if (t < 256) {
                    f32x4 v0 = *(const f32x4*)(Wgq + ((32 + q2) * G3 + 256 + col2) * 4);
                    *(f32x4*)(Bst + t * 4) = v0;
                    pf = *(const f32x4*)(Wgq + ((34 + q2) * G3 + 256 + col2) * 4);
                }
                __syncthreads();
                for (int ch = 0; ch < 16; ch++) {
                    const int cur = ch & 1;
                    if (t < 256) {
                        if (ch + 1 < 16) *(f32x4*)(Bst + (cur ^ 1) * 2048 + t * 4) = pf;
                        if (ch + 2 < 16) pf = *(const f32x4*)(Wgq + ((32 + 2 * (ch + 2) + q2) * G3 + 256 + col2) * 4);
                    }
                    __syncthreads();
                    const float* Bb = Bst + cur * 2048;
#pragma unroll
                    for (int kl = 0; kl < 2; kl++) {
                        const int kc = ch * 8 + kl * 4;
                        f32x4 bN[4];
#pragma unroll
                        for (int j = 0; j < 4; j++)
                            bN[j] = *(const f32x4*)(Bb + (kl * 128 + c32 + 32 * j) * 4);
#pragma unroll
                        for (int i = 0; i < 6; i++) {
                            if (i < nR) {
                                f32x4 a = *(const f32x4*)(hRM + (rowBase + i) * HSTR + kc);
#pragma unroll
                                for (int j = 0; j < 4; j++)
#pragma unroll
                                    for (int kk = 0; kk < 4; kk++)
                                        nh[i][j] = fmaf(a[kk], bN[j][kk], nh[i][j]);
                            }
                        }
                    }
                    __syncthreads();
                }
#pragma unroll
                for (int i = 0; i < 6; i++) {
                    if (i < nR) {
#pragma unroll
                        for (int j = 0; j < 4; j++)
                            tmp[i][j] = rg_[i][j] * (nh[i][j] + baseL[384 + c32 + 32 * j]);
                    }
                }
            }
            // ---- pass2b: ni over sm (k4 0..31, N cols) -> GRU epilogue
            {
                float ni[6][4];
#pragma unroll
                for (int i = 0; i < 6; i++)
#pragma unroll
                    for (int j = 0; j < 4; j++) ni[i][j] = 0.f;

                f32x4 pf;
                if (t < 256) {
                    f32x4 v0 = *(const f32x4*)(Wgq + (q2 * G3 + 256 + col2) * 4);
                    *(f32x4*)(Bst + t * 4) = v0;
                    pf = *(const f32x4*)(Wgq + ((2 + q2) * G3 + 256 + col2) * 4);
                }
                __syncthreads();
                for (int ch = 0; ch < 16; ch++) {
                    const int cur = ch & 1;
                    if (t < 256) {
                        if (ch + 1 < 16) *(f32x4*)(Bst + (cur ^ 1) * 2048 + t * 4) = pf;
                        if (ch + 2 < 16) pf = *(const f32x4*)(Wgq + ((2 * (ch + 2) + q2) * G3 + 256 + col2) * 4);
                    }
                    __syncthreads();
                    const float* Bb = Bst + cur * 2048;
#pragma unroll
                    for (int kl = 0; kl < 2; kl++) {
                        const int kc = ch * 8 + kl * 4;
                        f32x4 bN[4];
#pragma unroll
                        for (int j = 0; j < 4; j++)
                            bN[j] = *(const f32x4*)(Bb + (kl * 128 + c32 + 32 * j) * 4);
#pragma unroll
                        for (int i = 0; i < 6; i++) {
                            if (i < nR) {
                                f32x4 a = *(const f32x4*)(smRM + (rowBase + i) * HSTR + kc);
#pragma unroll
                                for (int j = 0; j < 4; j++)
#pragma unroll
                                    for (int kk = 0; kk < 4; kk++)
                                        ni[i][j] = fmaf(a[kk], bN[j][kk], ni[i][j]);
                            }
                        }
                    }
                    __syncthreads();
                }
                // all smRM/hRM reads done (last chunk barrier) -> safe to write h
#pragma unroll
                for (int i = 0; i < 6; i++) {
                    if (i < nR) {
                        int row = rowBase + i;
                        float cf = (float)(goffL[row + 1] - goffL[row]);
#pragma unroll
                        for (int j = 0; j < 4; j++) {
                            int cc = c32 + 32 * j;
                            float npre = ni[i][j] + baseL[256 + cc] + cf * extL[256 + cc] + tmp[i][j];
                            float ax = fabsf(npre);
                            float e  = __expf(-2.f * ax);
                            float tt = (1.f - e) / (1.f + e);
                            float n  = copysignf(tt, npre);
                            float ho = hRM[row * HSTR + cc];
                            hRM[row * HSTR + cc] = (1.f - z[i][j]) * n + z[i][j] * ho;
                        }
                    }
                }
            }
        }
        __syncthreads();   // B5: new h visible
    }

    // ======================= output head =======================
    // hid = relu(h @ W_o1^T + b_o1): thread -> cols c32+32j, its rows
    {
        float acc3[6][4];
#pragma unroll
        for (int i = 0; i < 6; i++)
#pragma unroll
            for (int j = 0; j < 4; j++) acc3[i][j] = 0.f;
        for (int kc = 0; kc < 128; kc += 4) {
            f32x4 bb[4];
#pragma unroll
            for (int j = 0; j < 4; j++)
                bb[j] = *(const f32x4*)(Wo1q + ((kc >> 2) * 128 + c32 + 32 * j) * 4);
#pragma unroll
            for (int i = 0; i < 6; i++) {
                if (i < nR) {
                    f32x4 a = *(const f32x4*)(hRM + (rowBase + i) * HSTR + kc);
#pragma unroll
                    for (int j = 0; j < 4; j++)
#pragma unroll
                        for (int kk = 0; kk < 4; kk++)
                            acc3[i][j] = fmaf(a[kk], bb[j][kk], acc3[i][j]);
                }
            }
        }
        __syncthreads();   // hRM reads done; reg2 -> hid
#pragma unroll
        for (int i = 0; i < 6; i++) {
            if (i < nR) {
                int row = rowBase + i;
#pragma unroll
                for (int j = 0; j < 4; j++) {
                    int cc = c32 + 32 * j;
                    reg2[row * HSTR + cc] = fmaxf(acc3[i][j] + b_o1[cc], 0.f);
                }
            }
        }
    }
    __syncthreads();
    // stage W_o2/b_o2 into hRM area (dead)
    {
        float* wo2L = hRM;
        float* bo2L = hRM + 1152;
        for (int i = t; i < 9 * HH; i += 512) wo2L[i] = W_o2[i];
        if (t < 9) bo2L[t] = b_o2[t];
    }
    __syncthreads();
    {
        const float* wo2L = hRM;
        const float* bo2L = hRM + 1152;
        for (int idx = t; idx < NN * 9; idx += 512) {
            int r = idx / 9, qq = idx - 9 * r;
            float acc = bo2L[qq];
            const float* hrow = reg2 + r * HSTR;
            const float* wrow = wo2L + qq * HH;
            for (int k = 0; k < HH; k++) acc = fmaf(hrow[k], wrow[k], acc);
            out[((long)b * NN + r) * 9 + qq] = acc;
        }
    }
}

// ---------------------------------------------------------------------------
extern "C" void kernel_launch(void* const* d_in, const int* in_sizes, int n_in,
                              void* d_out, int out_size, void* d_ws, size_t ws_size,
                              hipStream_t stream) {
    const float* x      = (const float*)d_in[0];
    const int* ei       = (const int*)d_in[1];
    const float* W_in   = (const float*)d_in[2];
    const float* b_in   = (const float*)d_in[3];
    const float* W_m1   = (const float*)d_in[4];
    const float* b_m1   = (const float*)d_in[5];
    const float* W_m2   = (const float*)d_in[6];
    const float* b_m2   = (const float*)d_in[7];
    const float* W_ih   = (const float*)d_in[8];
    const float* W_hh   = (const float*)d_in[9];
    const float* b_ih   = (const float*)d_in[10];
    const float* b_hh   = (const float*)d_in[11];
    const float* W_o1   = (const float*)d_in[12];
    const float* b_o1   = (const float*)d_in[13];
    const float* W_o2   = (const float*)d_in[14];
    const float* b_o2   = (const float*)d_in[15];
    float* out = (float*)d_out;

    char* ws = (char*)d_ws;
    size_t off = 0;
    auto alloc = [&](size_t bytes) -> char* {
        char* p = ws + off;
        off += (bytes + 255) & ~(size_t)255;
        return p;
    };
    float* Wc    = (float*)alloc((size_t)G3 * HH * 4);
    float* W1q   = (float*)alloc(128 * 256 * 4);
    float* Wgq   = (float*)alloc(256 * G3 * 4);
    float* Wo1q  = (float*)alloc(128 * 128 * 4);
    float* basev = (float*)alloc(512 * 4);
    float* extv  = (float*)alloc(512 * 4);
    int* goff    = (int*)alloc((NN + 1) * 4);
    int* gsend   = (int*)alloc(EE * 4);

    prep_graph<<<1, 128, 0, stream>>>(ei, goff, gsend);
    prep_wc<<<(G3 * HH + 255) / 256, 256, 0, stream>>>(W_ih, W_m2, Wc);
    prep_bias<<<2, 256, 0, stream>>>(W_ih, b_m2, b_ih, b_hh, basev, extv);
    prep_w1q<<<128, 256, 0, stream>>>(W_m1, W1q);
    prep_wgq<<<(256 * G3 + 255) / 256, 256, 0, stream>>>(Wc, W_hh, Wgq);
    prep_wo1q<<<64, 256, 0, stream>>>(W_o1, Wo1q);

    (void)hipFuncSetAttribute((const void*)fused_rrn,
                              hipFuncAttributeMaxDynamicSharedMemorySize,
                              (int)LDS_BYTES);
    fused_rrn<<<BB, 512, LDS_BYTES, stream>>>(
        x, W_in, b_in, b_m1, W1q, Wgq, basev, extv,
        Wo1q, b_o1, W_o2, b_o2, goff, gsend, out);
}

// Round 13
// 3312.757 us; speedup vs baseline: 1.4763x; 1.4763x over previous
//
#include <hip/hip_runtime.h>

#define BB 1024
#define NN 81
#define EE 1620
#define HH 128
#define G3 384
#define NSTEPS 8

#define HSTR 132     // hRM/smRM/hid row stride (floats)
#define ABSTR 260    // hAB row stride (floats)

typedef __attribute__((ext_vector_type(4))) float f32x4;

// ---- LDS float offsets ----
#define F_H     0            // hRM 81 x 132 = 10692
#define F_R2    10692        // 21060: union{ xs+win | hAB 81x260 | smRM 81x132 | hid 81x132 }
#define F_GOFF  31752        // 82 ints
#define F_GSEND 31834        // 1620 ushorts (810 float slots)
#define F_BM1   32644        // 128
#define F_BASE  32772        // 512
#define F_EXT   33284        // 512
#define F_TOT   33796
#define LDS_BYTES (F_TOT * 4)   // 135184 bytes

// ---------------------------------------------------------------------------
// prep_graph: CSR by receiver (int32 edge input) — verified R2/R4-R12.
// ---------------------------------------------------------------------------
__global__ __launch_bounds__(128) void prep_graph(const int* __restrict__ ei,
                                                  int* __restrict__ goff,
                                                  int* __restrict__ gsend) {
    __shared__ int eis[2 * EE];
    __shared__ int cs[NN];
    __shared__ int offs[NN + 1];
    int tid = threadIdx.x;
    for (int i = tid; i < 2 * EE; i += 128) eis[i] = ei[i];
    __syncthreads();
    if (tid < NN) {
        int c = 0;
        for (int e = 0; e < EE; e++) if (eis[EE + e] == tid) c++;
        cs[tid] = c;
    }
    __syncthreads();
    if (tid == 0) {
        int o = 0;
        for (int r = 0; r < NN; r++) { offs[r] = o; o += cs[r]; }
        offs[NN] = o;
    }
    __syncthreads();
    if (tid < NN) {
        int pos = offs[tid];
        for (int e = 0; e < EE; e++) {
            if (eis[EE + e] == tid) gsend[pos++] = eis[e];
        }
        goff[tid] = offs[tid];
    }
    if (tid == 0) goff[NN] = offs[NN];
}

// ---------------------------------------------------------------------------
// prep_wc: Wc[c][o] = sum_m W_ih[c][m] * W_m2[m][o]   (384 x 128)
// ---------------------------------------------------------------------------
__global__ __launch_bounds__(256) void prep_wc(const float* __restrict__ W_ih,
                                               const float* __restrict__ W_m2,
                                               float* __restrict__ Wc) {
    int idx = blockIdx.x * 256 + threadIdx.x;
    if (idx >= G3 * HH) return;
    int c = idx >> 7, o = idx & 127;
    float acc = 0.f;
    for (int m = 0; m < HH; m++) acc += W_ih[c * HH + m] * W_m2[m * HH + o];
    Wc[idx] = acc;
}

// ---------------------------------------------------------------------------
// prep_bias: base[512], ext[512]
// ---------------------------------------------------------------------------
__global__ __launch_bounds__(256) void prep_bias(const float* __restrict__ W_ih,
                                                 const float* __restrict__ b_m2,
                                                 const float* __restrict__ b_ih,
                                                 const float* __restrict__ b_hh,
                                                 float* __restrict__ basev,
                                                 float* __restrict__ extv) {
    int c = blockIdx.x * 256 + threadIdx.x;
    if (c >= 512) return;
    float base, ext;
    if (c < 384) {
        float bwc = 0.f;
        for (int m = 0; m < HH; m++) bwc += W_ih[c * HH + m] * b_m2[m];
        ext = bwc;
        base = (c < 256) ? (b_ih[c] + b_hh[c]) : b_ih[c];
    } else {
        ext = 0.f;
        base = b_hh[c - 128];
    }
    basev[c] = base;
    extv[c] = ext;
}

// ---------------------------------------------------------------------------
// prep_w1q: quad-packed W1: W1q[((k>>2)*256 + c)*4 + (k&3)] = W1[c][k]
// ---------------------------------------------------------------------------
__global__ __launch_bounds__(256) void prep_w1q(const float* __restrict__ W_m1,
                                                float* __restrict__ W1q) {
    int idx = blockIdx.x * 256 + threadIdx.x;   // 128*256
    if (idx >= 128 * 256) return;
    int k = idx >> 8, c = idx & 255;
    float v = (c < 128) ? W_m1[c * 256 + k] : W_m1[(c - 128) * 256 + 128 + k];
    W1q[((k >> 2) * 256 + c) * 4 + (k & 3)] = v;
}

// ---------------------------------------------------------------------------
// prep_wgq: quad-packed gates: Wgq[((k>>2)*384 + c)*4 + (k&3)]
//   = k<128 ? Wc[c][k] : W_hh[c][k-128]      (k in [0,256))
// ---------------------------------------------------------------------------
__global__ __launch_bounds__(256) void prep_wgq(const float* __restrict__ Wc,
                                                const float* __restrict__ W_hh,
                                                float* __restrict__ Wgq) {
    int idx = blockIdx.x * 256 + threadIdx.x;   // 256*384
    if (idx >= 256 * G3) return;
    int k = idx / G3;
    int c = idx - k * G3;
    float v = (k < 128) ? Wc[c * HH + k] : W_hh[c * HH + (k - 128)];
    Wgq[((k >> 2) * G3 + c) * 4 + (k & 3)] = v;
}

// ---------------------------------------------------------------------------
// prep_wo1q: Wo1q[((k>>2)*128 + c)*4 + (k&3)] = W_o1[c][k]
// ---------------------------------------------------------------------------
__global__ __launch_bounds__(256) void prep_wo1q(const float* __restrict__ W_o1,
                                                 float* __restrict__ Wo1q) {
    int idx = blockIdx.x * 256 + threadIdx.x;
    if (idx >= 128 * 128) return;
    int k = idx >> 7, c = idx & 127;
    Wo1q[((k >> 2) * 128 + c) * 4 + (k & 3)] = W_o1[c * HH + k];
}

// ---------------------------------------------------------------------------
// fused_rrn: one workgroup per puzzle, 512 threads (8 waves), fp32.
// R12 post-mortem: LDS B-staging spilled (prefetch regs over the 128 cap) and
// added 160 barriers/step -> reverted. R13 = R11 with 4 A-sweeps instead of 5:
//   P1: rr,zz over sm; then over h while ALSO accumulating nh (72 accums);
//       convert to rg_,z and tmp=rg_*(nh+b3) in place.
//   P2: ni over sm -> GRU epilogue.
// Same k-ascending order per accumulator as R11 => bit-identical output.
// B loads use uniform base (SALU-incrementable) + thread-const offsets.
// ---------------------------------------------------------------------------
__global__ __launch_bounds__(512, 2) void fused_rrn(
    const float* __restrict__ x,
    const float* __restrict__ W_in, const float* __restrict__ b_in,
    const float* __restrict__ b_m1,
    const float* __restrict__ W1q, const float* __restrict__ Wgq,
    const float* __restrict__ basev, const float* __restrict__ extv,
    const float* __restrict__ Wo1q, const float* __restrict__ b_o1,
    const float* __restrict__ W_o2, const float* __restrict__ b_o2,
    const int* __restrict__ goff_g, const int* __restrict__ gsend_g,
    float* __restrict__ out)
{
    extern __shared__ float smf[];
    float* hRM  = smf + F_H;
    float* reg2 = smf + F_R2;
    int*   goffL = (int*)(smf + F_GOFF);
    unsigned short* gsendL = (unsigned short*)(smf + F_GSEND);
    float* bm1L  = smf + F_BM1;
    float* baseL = smf + F_BASE;
    float* extL  = smf + F_EXT;

    const int t   = threadIdx.x;
    const int b   = blockIdx.x;
    const int c32 = t & 31;           // base gate column (cols c32+32j, j<4)
    const int g   = t >> 5;           // row group 0..15
    const int rowBase = g * 5;
    const int nR = (g == 15) ? 6 : 5;
    const int rW = t & 31;            // edge-phase row lane
    const int f8 = 8 * (t >> 5);      // edge-phase feature octet (0..120)
    const int tc4 = c32 * 4;          // thread-fixed float offset into quad rows

    // ---- stage misc + x/W_in (into reg2; used once) ----
    float* xsL  = reg2;          // 810
    float* winL = reg2 + 810;    // 1280
    for (int i = t; i < NN + 1; i += 512) goffL[i] = goff_g[i];
    for (int i = t; i < EE; i += 512) gsendL[i] = (unsigned short)gsend_g[i];
    baseL[t] = basev[t];
    extL[t]  = extv[t];
    if (t < 128) bm1L[t] = b_m1[t];
    for (int i = t; i < NN * 10; i += 512) xsL[i] = x[(long)b * (NN * 10) + i];
    for (int i = t; i < HH * 10; i += 512) winL[i] = W_in[i];
    __syncthreads();

    // ---- input projection: hRM[r][m] ----
    for (int idx = t; idx < NN * HH; idx += 512) {
        int r = idx >> 7, m = idx & 127;
        float acc = b_in[m];
#pragma unroll
        for (int k = 0; k < 10; k++) acc += xsL[r * 10 + k] * winL[m * 10 + k];
        hRM[r * HSTR + m] = acc;
    }
    __syncthreads();

    // ======================= 8 message-passing steps =======================
    for (int step = 0; step < NSTEPS; step++) {
        // ---------- GEMM1: hAB = h @ W1^T (cols c32+32j, 128+c32+32j) ----------
        {
            float accA[6][4], accB[6][4];
#pragma unroll
            for (int i = 0; i < 6; i++)
#pragma unroll
                for (int j = 0; j < 4; j++) { accA[i][j] = 0.f; accB[i][j] = 0.f; }
            for (int kc = 0; kc < 128; kc += 4) {
                const float* Bu = W1q + (kc >> 2) * (256 * 4);   // uniform base
                f32x4 bA[4], bB[4];
#pragma unroll
                for (int j = 0; j < 4; j++) {
                    bA[j] = *(const f32x4*)(Bu + tc4 + (32 * j) * 4);
                    bB[j] = *(const f32x4*)(Bu + tc4 + (128 + 32 * j) * 4);
                }
                const float* Ab = hRM + rowBase * HSTR + kc;
#pragma unroll
                for (int i = 0; i < 6; i++) {
                    if (i < nR) {
                        f32x4 a = *(const f32x4*)(Ab + i * HSTR);
#pragma unroll
                        for (int j = 0; j < 4; j++)
#pragma unroll
                            for (int kk = 0; kk < 4; kk++) {
                                accA[i][j] = fmaf(a[kk], bA[j][kk], accA[i][j]);
                                accB[i][j] = fmaf(a[kk], bB[j][kk], accB[i][j]);
                            }
                    }
                }
            }
            float* hAB = reg2;
#pragma unroll
            for (int i = 0; i < 6; i++) {
                if (i < nR) {
                    int row = rowBase + i;
#pragma unroll
                    for (int j = 0; j < 4; j++) {
                        hAB[row * ABSTR + c32 + 32 * j] = accA[i][j];
                        hAB[row * ABSTR + 128 + c32 + 32 * j] = accB[i][j];
                    }
                }
            }
        }
        __syncthreads();   // B1: hAB ready

        // ---------- edge aggregation: 3 rows x 8 features per thread ----------
        float sv[3][8];
        {
            float bq[8];
#pragma unroll
            for (int j = 0; j < 8; j++) bq[j] = bm1L[f8 + j];
#pragma unroll
            for (int s = 0; s < 3; s++) {
                int row = rW + 32 * s;
                if (row >= NN) {
#pragma unroll
                    for (int j = 0; j < 8; j++) sv[s][j] = 0.f;
                    continue;
                }
                int e0 = goffL[row], e1 = goffL[row + 1];
                f32x4 hb0 = *(const f32x4*)(reg2 + row * ABSTR + 128 + f8);
                f32x4 hb1 = *(const f32x4*)(reg2 + row * ABSTR + 128 + f8 + 4);
                float hbb[8], ac[8];
#pragma unroll
                for (int j = 0; j < 4; j++) {
                    hbb[j] = hb0[j] + bq[j];
                    hbb[4 + j] = hb1[j] + bq[4 + j];
                    ac[j] = 0.f; ac[4 + j] = 0.f;
                }
                for (int e = e0; e < e1; e++) {
                    int sn = gsendL[e];
                    f32x4 av0 = *(const f32x4*)(reg2 + sn * ABSTR + f8);
                    f32x4 av1 = *(const f32x4*)(reg2 + sn * ABSTR + f8 + 4);
#pragma unroll
                    for (int j = 0; j < 4; j++) {
                        ac[j]     += fmaxf(av0[j] + hbb[j], 0.f);
                        ac[4 + j] += fmaxf(av1[j] + hbb[4 + j], 0.f);
                    }
                }
#pragma unroll
                for (int j = 0; j < 8; j++) sv[s][j] = ac[j];
            }
        }
        __syncthreads();   // B2: hAB reads done, reg2 reusable as smRM
        {
#pragma unroll
            for (int s = 0; s < 3; s++) {
                int row = rW + 32 * s;
                if (row >= NN) continue;
                f32x4 v0 = {sv[s][0], sv[s][1], sv[s][2], sv[s][3]};
                f32x4 v1 = {sv[s][4], sv[s][5], sv[s][6], sv[s][7]};
                *(f32x4*)(reg2 + row * HSTR + f8) = v0;
                *(f32x4*)(reg2 + row * HSTR + f8 + 4) = v1;
            }
        }
        __syncthreads();   // B3: smRM ready

        // ---------- GEMM2: 2-pass schedule ----------
        {
            const float* smRM = reg2;
            float rr[6][4], zz[6][4], nh[6][4];
#pragma unroll
            for (int i = 0; i < 6; i++)
#pragma unroll
                for (int j = 0; j < 4; j++) { rr[i][j] = 0.f; zz[i][j] = 0.f; nh[i][j] = 0.f; }

            // ---- P1a: rr, zz over sm (Wgq rows kc>>2) ----
            for (int kc = 0; kc < 128; kc += 4) {
                const float* Bu = Wgq + (kc >> 2) * (G3 * 4);
                f32x4 bR[4], bZ[4];
#pragma unroll
                for (int j = 0; j < 4; j++) {
                    bR[j] = *(const f32x4*)(Bu + tc4 + (32 * j) * 4);
                    bZ[j] = *(const f32x4*)(Bu + tc4 + (128 + 32 * j) * 4);
                }
                const float* Ab = smRM + rowBase * HSTR + kc;
#pragma unroll
                for (int i = 0; i < 6; i++) {
                    if (i < nR) {
                        f32x4 a = *(const f32x4*)(Ab + i * HSTR);
#pragma unroll
                        for (int j = 0; j < 4; j++)
#pragma unroll
                            for (int kk = 0; kk < 4; kk++) {
                                rr[i][j] = fmaf(a[kk], bR[j][kk], rr[i][j]);
                                zz[i][j] = fmaf(a[kk], bZ[j][kk], zz[i][j]);
                            }
                    }
                }
            }
            // ---- P1b: rr, zz, nh over h (Wgq rows 32+(kc>>2)) ----
            for (int kc = 0; kc < 128; kc += 4) {
                const float* Bu = Wgq + (32 + (kc >> 2)) * (G3 * 4);
                const float* Ab = hRM + rowBase * HSTR + kc;
                // A rows first (shared by both gate groups)
                f32x4 a0, a1, a2, a3, a4, a5;
                a0 = *(const f32x4*)(Ab);
                a1 = *(const f32x4*)(Ab + HSTR);
                a2 = *(const f32x4*)(Ab + 2 * HSTR);
                a3 = *(const f32x4*)(Ab + 3 * HSTR);
                a4 = *(const f32x4*)(Ab + 4 * HSTR);
                f32x4 bR[4], bZ[4];
#pragma unroll
                for (int j = 0; j < 4; j++) {
                    bR[j] = *(const f32x4*)(Bu + tc4 + (32 * j) * 4);
                    bZ[j] = *(const f32x4*)(Bu + tc4 + (128 + 32 * j) * 4);
                }
#pragma unroll
                for (int j = 0; j < 4; j++)
#pragma unroll
                    for (int kk = 0; kk < 4; kk++) {
                        rr[0][j] = fmaf(a0[kk], bR[j][kk], rr[0][j]);
                        zz[0][j] = fmaf(a0[kk], bZ[j][kk], zz[0][j]);
                        rr[1][j] = fmaf(a1[kk], bR[j][kk], rr[1][j]);
                        zz[1][j] = fmaf(a1[kk], bZ[j][kk], zz[1][j]);
                        rr[2][j] = fmaf(a2[kk], bR[j][kk], rr[2][j]);
                        zz[2][j] = fmaf(a2[kk], bZ[j][kk], zz[2][j]);
                        rr[3][j] = fmaf(a3[kk], bR[j][kk], rr[3][j]);
                        zz[3][j] = fmaf(a3[kk], bZ[j][kk], zz[3][j]);
                        rr[4][j] = fmaf(a4[kk], bR[j][kk], rr[4][j]);
                        zz[4][j] = fmaf(a4[kk], bZ[j][kk], zz[4][j]);
                    }
                f32x4 bN[4];
#pragma unroll
                for (int j = 0; j < 4; j++)
                    bN[j] = *(const f32x4*)(Bu + tc4 + (256 + 32 * j) * 4);
#pragma unroll
                for (int j = 0; j < 4; j++)
#pragma unroll
                    for (int kk = 0; kk < 4; kk++) {
                        nh[0][j] = fmaf(a0[kk], bN[j][kk], nh[0][j]);
                        nh[1][j] = fmaf(a1[kk], bN[j][kk], nh[1][j]);
                        nh[2][j] = fmaf(a2[kk], bN[j][kk], nh[2][j]);
                        nh[3][j] = fmaf(a3[kk], bN[j][kk], nh[3][j]);
                        nh[4][j] = fmaf(a4[kk], bN[j][kk], nh[4][j]);
                    }
                if (nR == 6) {
                    a5 = *(const f32x4*)(Ab + 5 * HSTR);
#pragma unroll
                    for (int j = 0; j < 4; j++)
#pragma unroll
                        for (int kk = 0; kk < 4; kk++) {
                            rr[5][j] = fmaf(a5[kk], bR[j][kk], rr[5][j]);
                            zz[5][j] = fmaf(a5[kk], bZ[j][kk], zz[5][j]);
                            nh[5][j] = fmaf(a5[kk], bN[j][kk], nh[5][j]);
                        }
                }
            }
            // ---- gates r,z ; tmp = rg_*(nh+base3) in place ----
#pragma unroll
            for (int i = 0; i < 6; i++) {
                if (i < nR) {
                    int row = rowBase + i;
                    float cf = (float)(goffL[row + 1] - goffL[row]);
#pragma unroll
                    for (int j = 0; j < 4; j++) {
                        int cc = c32 + 32 * j;
                        float g0 = rr[i][j] + baseL[cc] + cf * extL[cc];
                        float g1 = zz[i][j] + baseL[128 + cc] + cf * extL[128 + cc];
                        float rg_ = 1.f / (1.f + __expf(-g0));
                        zz[i][j]  = 1.f / (1.f + __expf(-g1));       // z
                        nh[i][j]  = rg_ * (nh[i][j] + baseL[384 + cc]); // tmp
                    }
                }
            }
            // ---- P2: ni over sm (Wgq rows kc>>2, N cols) ----
            {
                float ni[6][4];
#pragma unroll
                for (int i = 0; i < 6; i++)
#pragma unroll
                    for (int j = 0; j < 4; j++) ni[i][j] = 0.f;
                for (int kc = 0; kc < 128; kc += 4) {
                    const float* Bu = Wgq + (kc >> 2) * (G3 * 4);
                    f32x4 bN[4];
#pragma unroll
                    for (int j = 0; j < 4; j++)
                        bN[j] = *(const f32x4*)(Bu + tc4 + (256 + 32 * j) * 4);
                    const float* Ab = smRM + rowBase * HSTR + kc;
#pragma unroll
                    for (int i = 0; i < 6; i++) {
                        if (i < nR) {
                            f32x4 a = *(const f32x4*)(Ab + i * HSTR);
#pragma unroll
                            for (int j = 0; j < 4; j++)
#pragma unroll
                                for (int kk = 0; kk < 4; kk++)
                                    ni[i][j] = fmaf(a[kk], bN[j][kk], ni[i][j]);
                        }
                    }
                }
                __syncthreads();   // B4: all smRM/hRM reads done before h writes

#pragma unroll
                for (int i = 0; i < 6; i++) {
                    if (i < nR) {
                        int row = rowBase + i;
                        float cf = (float)(goffL[row + 1] - goffL[row]);
#pragma unroll
                        for (int j = 0; j < 4; j++) {
                            int cc = c32 + 32 * j;
                            float npre = ni[i][j] + baseL[256 + cc] + cf * extL[256 + cc] + nh[i][j];
                            float ax = fabsf(npre);
                            float e  = __expf(-2.f * ax);
                            float tt = (1.f - e) / (1.f + e);
                            float n  = copysignf(tt, npre);
                            float ho = hRM[row * HSTR + cc];
                            hRM[row * HSTR + cc] = (1.f - zz[i][j]) * n + zz[i][j] * ho;
                        }
                    }
                }
            }
        }
        __syncthreads();   // B5: new h visible
    }

    // ======================= output head =======================
    // hid = relu(h @ W_o1^T + b_o1): thread -> cols c32+32j, its rows
    {
        float acc3[6][4];
#pragma unroll
        for (int i = 0; i < 6; i++)
#pragma unroll
            for (int j = 0; j < 4; j++) acc3[i][j] = 0.f;
        for (int kc = 0; kc < 128; kc += 4) {
            const float* Bu = Wo1q + (kc >> 2) * (128 * 4);
            f32x4 bb[4];
#pragma unroll
            for (int j = 0; j < 4; j++)
                bb[j] = *(const f32x4*)(Bu + tc4 + (32 * j) * 4);
            const float* Ab = hRM + rowBase * HSTR + kc;
#pragma unroll
            for (int i = 0; i < 6; i++) {
                if (i < nR) {
                    f32x4 a = *(const f32x4*)(Ab + i * HSTR);
#pragma unroll
                    for (int j = 0; j < 4; j++)
#pragma unroll
                        for (int kk = 0; kk < 4; kk++)
                            acc3[i][j] = fmaf(a[kk], bb[j][kk], acc3[i][j]);
                }
            }
        }
        __syncthreads();   // hRM reads done; reg2 -> hid
#pragma unroll
        for (int i = 0; i < 6; i++) {
            if (i < nR) {
                int row = rowBase + i;
#pragma unroll
                for (int j = 0; j < 4; j++) {
                    int cc = c32 + 32 * j;
                    reg2[row * HSTR + cc] = fmaxf(acc3[i][j] + b_o1[cc], 0.f);
                }
            }
        }
    }
    __syncthreads();
    // stage W_o2/b_o2 into hRM area (dead)
    {
        float* wo2L = hRM;
        float* bo2L = hRM + 1152;
        for (int i = t; i < 9 * HH; i += 512) wo2L[i] = W_o2[i];
        if (t < 9) bo2L[t] = b_o2[t];
    }
    __syncthreads();
    {
        const float* wo2L = hRM;
        const float* bo2L = hRM + 1152;
        for (int idx = t; idx < NN * 9; idx += 512) {
            int r = idx / 9, qq = idx - 9 * r;
            float acc = bo2L[qq];
            const float* hrow = reg2 + r * HSTR;
            const float* wrow = wo2L + qq * HH;
            for (int k = 0; k < HH; k++) acc = fmaf(hrow[k], wrow[k], acc);
            out[((long)b * NN + r) * 9 + qq] = acc;
        }
    }
}

// ---------------------------------------------------------------------------
extern "C" void kernel_launch(void* const* d_in, const int* in_sizes, int n_in,
                              void* d_out, int out_size, void* d_ws, size_t ws_size,
                              hipStream_t stream) {
    const float* x      = (const float*)d_in[0];
    const int* ei       = (const int*)d_in[1];
    const float* W_in   = (const float*)d_in[2];
    const float* b_in   = (const float*)d_in[3];
    const float* W_m1   = (const float*)d_in[4];
    const float* b_m1   = (const float*)d_in[5];
    const float* W_m2   = (const float*)d_in[6];
    const float* b_m2   = (const float*)d_in[7];
    const float* W_ih   = (const float*)d_in[8];
    const float* W_hh   = (const float*)d_in[9];
    const float* b_ih   = (const float*)d_in[10];
    const float* b_hh   = (const float*)d_in[11];
    const float* W_o1   = (const float*)d_in[12];
    const float* b_o1   = (const float*)d_in[13];
    const float* W_o2   = (const float*)d_in[14];
    const float* b_o2   = (const float*)d_in[15];
    float* out = (float*)d_out;

    char* ws = (char*)d_ws;
    size_t off = 0;
    auto alloc = [&](size_t bytes) -> char* {
        char* p = ws + off;
        off += (bytes + 255) & ~(size_t)255;
        return p;
    };
    float* Wc    = (float*)alloc((size_t)G3 * HH * 4);
    float* W1q   = (float*)alloc(128 * 256 * 4);
    float* Wgq   = (float*)alloc(256 * G3 * 4);
    float* Wo1q  = (float*)alloc(128 * 128 * 4);
    float* basev = (float*)alloc(512 * 4);
    float* extv  = (float*)alloc(512 * 4);
    int* goff    = (int*)alloc((NN + 1) * 4);
    int* gsend   = (int*)alloc(EE * 4);

    prep_graph<<<1, 128, 0, stream>>>(ei, goff, gsend);
    prep_wc<<<(G3 * HH + 255) / 256, 256, 0, stream>>>(W_ih, W_m2, Wc);
    prep_bias<<<2, 256, 0, stream>>>(W_ih, b_m2, b_ih, b_hh, basev, extv);
    prep_w1q<<<128, 256, 0, stream>>>(W_m1, W1q);
    prep_wgq<<<(256 * G3 + 255) / 256, 256, 0, stream>>>(Wc, W_hh, Wgq);
    prep_wo1q<<<64, 256, 0, stream>>>(W_o1, Wo1q);

    (void)hipFuncSetAttribute((const void*)fused_rrn,
                              hipFuncAttributeMaxDynamicSharedMemorySize,
                              (int)LDS_BYTES);
    fused_rrn<<<BB, 512, LDS_BYTES, stream>>>(
        x, W_in, b_in, b_m1, W1q, Wgq, basev, extv,
        Wo1q, b_o1, W_o2, b_o2, goff, gsend, out);
}

// Round 14
// 3063.842 us; speedup vs baseline: 1.5962x; 1.0812x over previous
//
#include <hip/hip_runtime.h>

#define BB 1024
#define NN 81
#define EE 1620
#define HH 128
#define G3 384
#define NSTEPS 8

#define HSTR 132     // hRM/smRM/hid row stride (floats)
#define ABSTR 260    // hAB row stride (floats)

typedef __attribute__((ext_vector_type(4))) float f32x4;

// ---- LDS float offsets ----
#define F_H     0            // hRM 81 x 132 = 10692
#define F_R2    10692        // 21060: union{ xs+win | hAB 81x260 | smRM 81x132 | hid 81x132 }
#define F_GOFF  31752        // 82 ints
#define F_GSEND 31834        // 1620 ushorts (810 float slots)
#define F_BM1   32644        // 128
#define F_BASE  32772        // 512
#define F_EXT   33284        // 512
#define F_TOT   33796
#define LDS_BYTES (F_TOT * 4)   // 135184 bytes

// ---------------------------------------------------------------------------
// prep_graph: CSR by receiver (int32 edge input) — verified R2/R4-R13.
// ---------------------------------------------------------------------------
__global__ __launch_bounds__(128) void prep_graph(const int* __restrict__ ei,
                                                  int* __restrict__ goff,
                                                  int* __restrict__ gsend) {
    __shared__ int eis[2 * EE];
    __shared__ int cs[NN];
    __shared__ int offs[NN + 1];
    int tid = threadIdx.x;
    for (int i = tid; i < 2 * EE; i += 128) eis[i] = ei[i];
    __syncthreads();
    if (tid < NN) {
        int c = 0;
        for (int e = 0; e < EE; e++) if (eis[EE + e] == tid) c++;
        cs[tid] = c;
    }
    __syncthreads();
    if (tid == 0) {
        int o = 0;
        for (int r = 0; r < NN; r++) { offs[r] = o; o += cs[r]; }
        offs[NN] = o;
    }
    __syncthreads();
    if (tid < NN) {
        int pos = offs[tid];
        for (int e = 0; e < EE; e++) {
            if (eis[EE + e] == tid) gsend[pos++] = eis[e];
        }
        goff[tid] = offs[tid];
    }
    if (tid == 0) goff[NN] = offs[NN];
}

// ---------------------------------------------------------------------------
// prep_wc: Wc[c][o] = sum_m W_ih[c][m] * W_m2[m][o]   (384 x 128)
// ---------------------------------------------------------------------------
__global__ __launch_bounds__(256) void prep_wc(const float* __restrict__ W_ih,
                                               const float* __restrict__ W_m2,
                                               float* __restrict__ Wc) {
    int idx = blockIdx.x * 256 + threadIdx.x;
    if (idx >= G3 * HH) return;
    int c = idx >> 7, o = idx & 127;
    float acc = 0.f;
    for (int m = 0; m < HH; m++) acc += W_ih[c * HH + m] * W_m2[m * HH + o];
    Wc[idx] = acc;
}

// ---------------------------------------------------------------------------
// prep_bias: base[512], ext[512]
// ---------------------------------------------------------------------------
__global__ __launch_bounds__(256) void prep_bias(const float* __restrict__ W_ih,
                                                 const float* __restrict__ b_m2,
                                                 const float* __restrict__ b_ih,
                                                 const float* __restrict__ b_hh,
                                                 float* __restrict__ basev,
                                                 float* __restrict__ extv) {
    int c = blockIdx.x * 256 + threadIdx.x;
    if (c >= 512) return;
    float base, ext;
    if (c < 384) {
        float bwc = 0.f;
        for (int m = 0; m < HH; m++) bwc += W_ih[c * HH + m] * b_m2[m];
        ext = bwc;
        base = (c < 256) ? (b_ih[c] + b_hh[c]) : b_ih[c];
    } else {
        ext = 0.f;
        base = b_hh[c - 128];
    }
    basev[c] = base;
    extv[c] = ext;
}

// ---------------------------------------------------------------------------
// prep_w1q: quad-packed W1: W1q[((k>>2)*256 + c)*4 + (k&3)] = W1[c][k]
// ---------------------------------------------------------------------------
__global__ __launch_bounds__(256) void prep_w1q(const float* __restrict__ W_m1,
                                                float* __restrict__ W1q) {
    int idx = blockIdx.x * 256 + threadIdx.x;   // 128*256
    if (idx >= 128 * 256) return;
    int k = idx >> 8, c = idx & 255;
    float v = (c < 128) ? W_m1[c * 256 + k] : W_m1[(c - 128) * 256 + 128 + k];
    W1q[((k >> 2) * 256 + c) * 4 + (k & 3)] = v;
}

// ---------------------------------------------------------------------------
// prep_wgq: quad-packed gates: Wgq[((k>>2)*384 + c)*4 + (k&3)]
//   = k<128 ? Wc[c][k] : W_hh[c][k-128]      (k in [0,256))
// ---------------------------------------------------------------------------
__global__ __launch_bounds__(256) void prep_wgq(const float* __restrict__ Wc,
                                                const float* __restrict__ W_hh,
                                                float* __restrict__ Wgq) {
    int idx = blockIdx.x * 256 + threadIdx.x;   // 256*384
    if (idx >= 256 * G3) return;
    int k = idx / G3;
    int c = idx - k * G3;
    float v = (k < 128) ? Wc[c * HH + k] : W_hh[c * HH + (k - 128)];
    Wgq[((k >> 2) * G3 + c) * 4 + (k & 3)] = v;
}

// ---------------------------------------------------------------------------
// prep_wo1q: Wo1q[((k>>2)*128 + c)*4 + (k&3)] = W_o1[c][k]
// ---------------------------------------------------------------------------
__global__ __launch_bounds__(256) void prep_wo1q(const float* __restrict__ W_o1,
                                                 float* __restrict__ Wo1q) {
    int idx = blockIdx.x * 256 + threadIdx.x;
    if (idx >= 128 * 128) return;
    int k = idx >> 7, c = idx & 127;
    Wo1q[((k >> 2) * 128 + c) * 4 + (k & 3)] = W_o1[c * HH + k];
}

// ---------------------------------------------------------------------------
// fused_rrn: one workgroup per puzzle, 512 threads (8 waves), fp32.
// R13 post-mortem: per-step cycle budget showed B-panel L1 reads (32 dwordx4
// per thread per kc) are the largest pipe (~131K cyc/step vs FMA 88K).
// R14: 8 groups x 64 col-threads (wave = group). Thread owns 6 gate cols
// {c64+64j} and 10-11 rows -> B insts per kc halve (16), wave B loads are
// 1KB fully-coalesced, A-reads are wave-uniform LDS broadcasts.
// Same k-ascending accumulation order as R13 => bit-identical output.
// ---------------------------------------------------------------------------
__global__ __launch_bounds__(512, 2) void fused_rrn(
    const float* __restrict__ x,
    const float* __restrict__ W_in, const float* __restrict__ b_in,
    const float* __restrict__ b_m1,
    const float* __restrict__ W1q, const float* __restrict__ Wgq,
    const float* __restrict__ basev, const float* __restrict__ extv,
    const float* __restrict__ Wo1q, const float* __restrict__ b_o1,
    const float* __restrict__ W_o2, const float* __restrict__ b_o2,
    const int* __restrict__ goff_g, const int* __restrict__ gsend_g,
    float* __restrict__ out)
{
    extern __shared__ float smf[];
    float* hRM  = smf + F_H;
    float* reg2 = smf + F_R2;
    int*   goffL = (int*)(smf + F_GOFF);
    unsigned short* gsendL = (unsigned short*)(smf + F_GSEND);
    float* bm1L  = smf + F_BM1;
    float* baseL = smf + F_BASE;
    float* extL  = smf + F_EXT;

    const int t   = threadIdx.x;
    const int b   = blockIdx.x;
    const int c64 = t & 63;           // base gate column (cols c64+64j)
    const int g   = t >> 6;           // row group 0..7 (== wave id)
    const int rowBase = g * 10;
    const int nR = (g == 7) ? 11 : 10;
    const int rW = t & 31;            // edge-phase row lane
    const int f8 = 8 * (t >> 5);      // edge-phase feature octet (0..120)
    const int tc4 = c64 * 4;          // thread-fixed float offset into quad rows

    // ---- stage misc + x/W_in (into reg2; used once) ----
    float* xsL  = reg2;          // 810
    float* winL = reg2 + 810;    // 1280
    for (int i = t; i < NN + 1; i += 512) goffL[i] = goff_g[i];
    for (int i = t; i < EE; i += 512) gsendL[i] = (unsigned short)gsend_g[i];
    baseL[t] = basev[t];
    extL[t]  = extv[t];
    if (t < 128) bm1L[t] = b_m1[t];
    for (int i = t; i < NN * 10; i += 512) xsL[i] = x[(long)b * (NN * 10) + i];
    for (int i = t; i < HH * 10; i += 512) winL[i] = W_in[i];
    __syncthreads();

    // ---- input projection: hRM[r][m] ----
    for (int idx = t; idx < NN * HH; idx += 512) {
        int r = idx >> 7, m = idx & 127;
        float acc = b_in[m];
#pragma unroll
        for (int k = 0; k < 10; k++) acc += xsL[r * 10 + k] * winL[m * 10 + k];
        hRM[r * HSTR + m] = acc;
    }
    __syncthreads();

    // ======================= 8 message-passing steps =======================
    for (int step = 0; step < NSTEPS; step++) {
        // ---------- GEMM1: hAB = h @ W1^T (cols c64+64j, j<4) ----------
        {
            float accA[11][2], accB[11][2];
#pragma unroll
            for (int i = 0; i < 11; i++) {
                accA[i][0] = 0.f; accA[i][1] = 0.f;
                accB[i][0] = 0.f; accB[i][1] = 0.f;
            }
            for (int kc = 0; kc < 128; kc += 4) {
                const float* Bu = W1q + (kc >> 2) * (256 * 4);
                f32x4 bA[2], bB[2];
#pragma unroll
                for (int j = 0; j < 2; j++) {
                    bA[j] = *(const f32x4*)(Bu + tc4 + (64 * j) * 4);
                    bB[j] = *(const f32x4*)(Bu + tc4 + (128 + 64 * j) * 4);
                }
                const float* Ab = hRM + rowBase * HSTR + kc;
#pragma unroll
                for (int i = 0; i < 11; i++) {
                    if (i < nR) {
                        f32x4 a = *(const f32x4*)(Ab + i * HSTR);
#pragma unroll
                        for (int j = 0; j < 2; j++)
#pragma unroll
                            for (int kk = 0; kk < 4; kk++) {
                                accA[i][j] = fmaf(a[kk], bA[j][kk], accA[i][j]);
                                accB[i][j] = fmaf(a[kk], bB[j][kk], accB[i][j]);
                            }
                    }
                }
            }
            float* hAB = reg2;
#pragma unroll
            for (int i = 0; i < 11; i++) {
                if (i < nR) {
                    int row = rowBase + i;
#pragma unroll
                    for (int j = 0; j < 2; j++) {
                        hAB[row * ABSTR + c64 + 64 * j] = accA[i][j];
                        hAB[row * ABSTR + 128 + c64 + 64 * j] = accB[i][j];
                    }
                }
            }
        }
        __syncthreads();   // B1: hAB ready

        // ---------- edge aggregation: 3 rows x 8 features per thread ----------
        float sv[3][8];
        {
            float bq[8];
#pragma unroll
            for (int j = 0; j < 8; j++) bq[j] = bm1L[f8 + j];
#pragma unroll
            for (int s = 0; s < 3; s++) {
                int row = rW + 32 * s;
                if (row >= NN) {
#pragma unroll
                    for (int j = 0; j < 8; j++) sv[s][j] = 0.f;
                    continue;
                }
                int e0 = goffL[row], e1 = goffL[row + 1];
                f32x4 hb0 = *(const f32x4*)(reg2 + row * ABSTR + 128 + f8);
                f32x4 hb1 = *(const f32x4*)(reg2 + row * ABSTR + 128 + f8 + 4);
                float hbb[8], ac[8];
#pragma unroll
                for (int j = 0; j < 4; j++) {
                    hbb[j] = hb0[j] + bq[j];
                    hbb[4 + j] = hb1[j] + bq[4 + j];
                    ac[j] = 0.f; ac[4 + j] = 0.f;
                }
                for (int e = e0; e < e1; e++) {
                    int sn = gsendL[e];
                    f32x4 av0 = *(const f32x4*)(reg2 + sn * ABSTR + f8);
                    f32x4 av1 = *(const f32x4*)(reg2 + sn * ABSTR + f8 + 4);
#pragma unroll
                    for (int j = 0; j < 4; j++) {
                        ac[j]     += fmaxf(av0[j] + hbb[j], 0.f);
                        ac[4 + j] += fmaxf(av1[j] + hbb[4 + j], 0.f);
                    }
                }
#pragma unroll
                for (int j = 0; j < 8; j++) sv[s][j] = ac[j];
            }
        }
        __syncthreads();   // B2: hAB reads done, reg2 reusable as smRM
        {
#pragma unroll
            for (int s = 0; s < 3; s++) {
                int row = rW + 32 * s;
                if (row >= NN) continue;
                f32x4 v0 = {sv[s][0], sv[s][1], sv[s][2], sv[s][3]};
                f32x4 v1 = {sv[s][4], sv[s][5], sv[s][6], sv[s][7]};
                *(f32x4*)(reg2 + row * HSTR + f8) = v0;
                *(f32x4*)(reg2 + row * HSTR + f8 + 4) = v1;
            }
        }
        __syncthreads();   // B3: smRM ready

        // ---------- GEMM2: 2-pass schedule (cols c64+64j) ----------
        {
            const float* smRM = reg2;
            float rr[11][2], zz[11][2], nh[11][2];
#pragma unroll
            for (int i = 0; i < 11; i++) {
                rr[i][0] = 0.f; rr[i][1] = 0.f;
                zz[i][0] = 0.f; zz[i][1] = 0.f;
                nh[i][0] = 0.f; nh[i][1] = 0.f;
            }

            // ---- P1a: rr, zz over sm (Wgq rows kc>>2) ----
            for (int kc = 0; kc < 128; kc += 4) {
                const float* Bu = Wgq + (kc >> 2) * (G3 * 4);
                f32x4 bR[2], bZ[2];
#pragma unroll
                for (int j = 0; j < 2; j++) {
                    bR[j] = *(const f32x4*)(Bu + tc4 + (64 * j) * 4);
                    bZ[j] = *(const f32x4*)(Bu + tc4 + (128 + 64 * j) * 4);
                }
                const float* Ab = smRM + rowBase * HSTR + kc;
#pragma unroll
                for (int i = 0; i < 11; i++) {
                    if (i < nR) {
                        f32x4 a = *(const f32x4*)(Ab + i * HSTR);
#pragma unroll
                        for (int j = 0; j < 2; j++)
#pragma unroll
                            for (int kk = 0; kk < 4; kk++) {
                                rr[i][j] = fmaf(a[kk], bR[j][kk], rr[i][j]);
                                zz[i][j] = fmaf(a[kk], bZ[j][kk], zz[i][j]);
                            }
                    }
                }
            }
            // ---- P1b: rr, zz, nh over h (Wgq rows 32+(kc>>2)) ----
            for (int kc = 0; kc < 128; kc += 4) {
                const float* Bu = Wgq + (32 + (kc >> 2)) * (G3 * 4);
                f32x4 bR[2], bZ[2], bN[2];
#pragma unroll
                for (int j = 0; j < 2; j++) {
                    bR[j] = *(const f32x4*)(Bu + tc4 + (64 * j) * 4);
                    bZ[j] = *(const f32x4*)(Bu + tc4 + (128 + 64 * j) * 4);
                    bN[j] = *(const f32x4*)(Bu + tc4 + (256 + 64 * j) * 4);
                }
                const float* Ab = hRM + rowBase * HSTR + kc;
#pragma unroll
                for (int i = 0; i < 11; i++) {
                    if (i < nR) {
                        f32x4 a = *(const f32x4*)(Ab + i * HSTR);
#pragma unroll
                        for (int j = 0; j < 2; j++)
#pragma unroll
                            for (int kk = 0; kk < 4; kk++) {
                                rr[i][j] = fmaf(a[kk], bR[j][kk], rr[i][j]);
                                zz[i][j] = fmaf(a[kk], bZ[j][kk], zz[i][j]);
                                nh[i][j] = fmaf(a[kk], bN[j][kk], nh[i][j]);
                            }
                    }
                }
            }
            // ---- gates r,z ; tmp = rg_*(nh+base3) in place ----
#pragma unroll
            for (int i = 0; i < 11; i++) {
                if (i < nR) {
                    int row = rowBase + i;
                    float cf = (float)(goffL[row + 1] - goffL[row]);
#pragma unroll
                    for (int j = 0; j < 2; j++) {
                        int cc = c64 + 64 * j;
                        float g0 = rr[i][j] + baseL[cc] + cf * extL[cc];
                        float g1 = zz[i][j] + baseL[128 + cc] + cf * extL[128 + cc];
                        float rg_ = 1.f / (1.f + __expf(-g0));
                        zz[i][j]  = 1.f / (1.f + __expf(-g1));          // z
                        nh[i][j]  = rg_ * (nh[i][j] + baseL[384 + cc]); // tmp
                    }
                }
            }
            // ---- P2: ni over sm (Wgq rows kc>>2, N cols) ----
            {
                float ni[11][2];
#pragma unroll
                for (int i = 0; i < 11; i++) { ni[i][0] = 0.f; ni[i][1] = 0.f; }
                for (int kc = 0; kc < 128; kc += 4) {
                    const float* Bu = Wgq + (kc >> 2) * (G3 * 4);
                    f32x4 bN[2];
#pragma unroll
                    for (int j = 0; j < 2; j++)
                        bN[j] = *(const f32x4*)(Bu + tc4 + (256 + 64 * j) * 4);
                    const float* Ab = smRM + rowBase * HSTR + kc;
#pragma unroll
                    for (int i = 0; i < 11; i++) {
                        if (i < nR) {
                            f32x4 a = *(const f32x4*)(Ab + i * HSTR);
#pragma unroll
                            for (int j = 0; j < 2; j++)
#pragma unroll
                                for (int kk = 0; kk < 4; kk++)
                                    ni[i][j] = fmaf(a[kk], bN[j][kk], ni[i][j]);
                        }
                    }
                }
                __syncthreads();   // B4: all smRM/hRM reads done before h writes

#pragma unroll
                for (int i = 0; i < 11; i++) {
                    if (i < nR) {
                        int row = rowBase + i;
                        float cf = (float)(goffL[row + 1] - goffL[row]);
#pragma unroll
                        for (int j = 0; j < 2; j++) {
                            int cc = c64 + 64 * j;
                            float npre = ni[i][j] + baseL[256 + cc] + cf * extL[256 + cc] + nh[i][j];
                            float ax = fabsf(npre);
                            float e  = __expf(-2.f * ax);
                            float tt = (1.f - e) / (1.f + e);
                            float n  = copysignf(tt, npre);
                            float ho = hRM[row * HSTR + cc];
                            hRM[row * HSTR + cc] = (1.f - zz[i][j]) * n + zz[i][j] * ho;
                        }
                    }
                }
            }
        }
        __syncthreads();   // B5: new h visible
    }

    // ======================= output head =======================
    // hid = relu(h @ W_o1^T + b_o1): thread -> cols c64+64j (j<2), its rows
    {
        float acc3[11][2];
#pragma unroll
        for (int i = 0; i < 11; i++) { acc3[i][0] = 0.f; acc3[i][1] = 0.f; }
        for (int kc = 0; kc < 128; kc += 4) {
            const float* Bu = Wo1q + (kc >> 2) * (128 * 4);
            f32x4 bb[2];
#pragma unroll
            for (int j = 0; j < 2; j++)
                bb[j] = *(const f32x4*)(Bu + tc4 + (64 * j) * 4);
            const float* Ab = hRM + rowBase * HSTR + kc;
#pragma unroll
            for (int i = 0; i < 11; i++) {
                if (i < nR) {
                    f32x4 a = *(const f32x4*)(Ab + i * HSTR);
#pragma unroll
                    for (int j = 0; j < 2; j++)
#pragma unroll
                        for (int kk = 0; kk < 4; kk++)
                            acc3[i][j] = fmaf(a[kk], bb[j][kk], acc3[i][j]);
                }
            }
        }
        __syncthreads();   // hRM reads done; reg2 -> hid
#pragma unroll
        for (int i = 0; i < 11; i++) {
            if (i < nR) {
                int row = rowBase + i;
#pragma unroll
                for (int j = 0; j < 2; j++) {
                    int cc = c64 + 64 * j;
                    reg2[row * HSTR + cc] = fmaxf(acc3[i][j] + b_o1[cc], 0.f);
                }
            }
        }
    }
    __syncthreads();
    // stage W_o2/b_o2 into hRM area (dead)
    {
        float* wo2L = hRM;
        float* bo2L = hRM + 1152;
        for (int i = t; i < 9 * HH; i += 512) wo2L[i] = W_o2[i];
        if (t < 9) bo2L[t] = b_o2[t];
    }
    __syncthreads();
    {
        const float* wo2L = hRM;
        const float* bo2L = hRM + 1152;
        for (int idx = t; idx < NN * 9; idx += 512) {
            int r = idx / 9, qq = idx - 9 * r;
            float acc = bo2L[qq];
            const float* hrow = reg2 + r * HSTR;
            const float* wrow = wo2L + qq * HH;
            for (int k = 0; k < HH; k++) acc = fmaf(hrow[k], wrow[k], acc);
            out[((long)b * NN + r) * 9 + qq] = acc;
        }
    }
}

// ---------------------------------------------------------------------------
extern "C" void kernel_launch(void* const* d_in, const int* in_sizes, int n_in,
                              void* d_out, int out_size, void* d_ws, size_t ws_size,
                              hipStream_t stream) {
    const float* x      = (const float*)d_in[0];
    const int* ei       = (const int*)d_in[1];
    const float* W_in   = (const float*)d_in[2];
    const float* b_in   = (const float*)d_in[3];
    const float* W_m1   = (const float*)d_in[4];
    const float* b_m1   = (const float*)d_in[5];
    const float* W_m2   = (const float*)d_in[6];
    const float* b_m2   = (const float*)d_in[7];
    const float* W_ih   = (const float*)d_in[8];
    const float* W_hh   = (const float*)d_in[9];
    const float* b_ih   = (const float*)d_in[10];
    const float* b_hh   = (const float*)d_in[11];
    const float* W_o1   = (const float*)d_in[12];
    const float* b_o1   = (const float*)d_in[13];
    const float* W_o2   = (const float*)d_in[14];
    const float* b_o2   = (const float*)d_in[15];
    float* out = (float*)d_out;

    char* ws = (char*)d_ws;
    size_t off = 0;
    auto alloc = [&](size_t bytes) -> char* {
        char* p = ws + off;
        off += (bytes + 255) & ~(size_t)255;
        return p;
    };
    float* Wc    = (float*)alloc((size_t)G3 * HH * 4);
    float* W1q   = (float*)alloc(128 * 256 * 4);
    float* Wgq   = (float*)alloc(256 * G3 * 4);
    float* Wo1q  = (float*)alloc(128 * 128 * 4);
    float* basev = (float*)alloc(512 * 4);
    float* extv  = (float*)alloc(512 * 4);
    int* goff    = (int*)alloc((NN + 1) * 4);
    int* gsend   = (int*)alloc(EE * 4);

    prep_graph<<<1, 128, 0, stream>>>(ei, goff, gsend);
    prep_wc<<<(G3 * HH + 255) / 256, 256, 0, stream>>>(W_ih, W_m2, Wc);
    prep_bias<<<2, 256, 0, stream>>>(W_ih, b_m2, b_ih, b_hh, basev, extv);
    prep_w1q<<<128, 256, 0, stream>>>(W_m1, W1q);
    prep_wgq<<<(256 * G3 + 255) / 256, 256, 0, stream>>>(Wc, W_hh, Wgq);
    prep_wo1q<<<64, 256, 0, stream>>>(W_o1, Wo1q);

    (void)hipFuncSetAttribute((const void*)fused_rrn,
                              hipFuncAttributeMaxDynamicSharedMemorySize,
                              (int)LDS_BYTES);
    fused_rrn<<<BB, 512, LDS_BYTES, stream>>>(
        x, W_in, b_in, b_m1, W1q, Wgq, basev, extv,
        Wo1q, b_o1, W_o2, b_o2, goff, gsend, out);
}